// Round 1
// baseline (775.196 us; speedup 1.0000x reference)
//
#include <hip/hip_runtime.h>
#include <math.h>

// GCN: out = D^-1/2 (A+I) D^-1/2 (x W^T) + b per layer, ReLU between layers.
// Strategy: build CSR (by dst) once per call; per layer: fp32 tiled GEMM with
// dinv folded into epilogue (g = dinv .* (x W^T)), then wave-per-node
// gather-sum over in-edges + self, epilogue y = dinv*sum + b (+ReLU).

// ---------------- graph build ----------------

// Detect whether edge_index is stored as int64 (hi words of nonneg values == 0)
__global__ __launch_bounds__(256) void k_detect(const int* __restrict__ ei, int* __restrict__ flag, int E) {
  __shared__ int nonzero;
  if (threadIdx.x == 0) nonzero = 0;
  __syncthreads();
  int idx = threadIdx.x;
  if (idx < E && idx < 256) {
    if (ei[2 * idx + 1] != 0) atomicOr(&nonzero, 1);
  }
  __syncthreads();
  if (threadIdx.x == 0) *flag = (nonzero == 0) ? 1 : 0;  // 1 => int64 layout
}

__device__ __forceinline__ int edge_at(const void* ei, int is64, long long idx) {
  if (is64) return (int)((const long long*)ei)[idx];
  return ((const int*)ei)[idx];
}

__global__ __launch_bounds__(256) void k_hist(const void* __restrict__ ei, const int* __restrict__ flag,
                                              int* __restrict__ deg, int E, int n) {
  int i = blockIdx.x * 256 + threadIdx.x;
  if (i >= E) return;
  int is64 = *flag;
  int v = edge_at(ei, is64, (long long)E + i);  // dst row
  if ((unsigned)v < (unsigned)n) atomicAdd(&deg[v], 1);
}

__global__ __launch_bounds__(256) void k_dinv(const int* __restrict__ deg, float* __restrict__ dinv, int n) {
  int i = blockIdx.x * 256 + threadIdx.x;
  if (i < n) dinv[i] = 1.0f / sqrtf((float)(deg[i] + 1));  // +1 self-loop; always > 0
}

__global__ __launch_bounds__(1024) void k_scan(const int* __restrict__ deg, int* __restrict__ row_ptr, int n) {
  __shared__ int buf[1024];
  __shared__ int carry_s;
  if (threadIdx.x == 0) { carry_s = 0; row_ptr[0] = 0; }
  __syncthreads();
  for (int base = 0; base < n; base += 1024) {
    int i = base + (int)threadIdx.x;
    int v = (i < n) ? deg[i] : 0;
    buf[threadIdx.x] = v;
    __syncthreads();
    for (int off = 1; off < 1024; off <<= 1) {
      int t = (threadIdx.x >= (unsigned)off) ? buf[threadIdx.x - off] : 0;
      __syncthreads();
      buf[threadIdx.x] += t;
      __syncthreads();
    }
    if (i < n) row_ptr[i + 1] = carry_s + buf[threadIdx.x];
    __syncthreads();
    if (threadIdx.x == 0) carry_s += buf[1023];
    __syncthreads();
  }
}

__global__ __launch_bounds__(256) void k_fill(const void* __restrict__ ei, const int* __restrict__ flag,
                                              const int* __restrict__ row_ptr, int* __restrict__ fill,
                                              int* __restrict__ col, int E, int n) {
  int i = blockIdx.x * 256 + threadIdx.x;
  if (i >= E) return;
  int is64 = *flag;
  int s = edge_at(ei, is64, i);                  // src row
  int v = edge_at(ei, is64, (long long)E + i);   // dst row
  if ((unsigned)v < (unsigned)n && (unsigned)s < (unsigned)n) {
    int pos = atomicAdd(&fill[v], 1);
    col[row_ptr[v] + pos] = s;
  }
}

// ---------------- GEMM: G[n,DO] = dinv[:,None] * (A[n,128] @ W[DO,128]^T) ----------------
// 128-row tile, BK=32, 256 threads, 8x(DO/16) per thread, strided row/col
// assignment (i = trow + 16r, j = tcol + 16c) for conflict-free b128 LDS reads
// with stride 36 floats (16B-aligned, superbank varies with trow/tcol).

template <int DO>
__global__ __launch_bounds__(256) void gemm_xwt(const float* __restrict__ A, const float* __restrict__ Wt,
                                                const float* __restrict__ dinv, float* __restrict__ G, int n) {
  constexpr int BK = 32;
  constexpr int SS = BK + 4;   // 36 floats: keeps float4 alignment, spreads superbanks
  constexpr int NC = DO / 16;
  __shared__ float sA[128][SS];
  __shared__ float sW[DO][SS];
  const int tid = threadIdx.x;
  const int trow = tid >> 4;   // 0..15
  const int tcol = tid & 15;   // 0..15
  const int brow = blockIdx.x * 128;

  float acc[8][NC];
#pragma unroll
  for (int r = 0; r < 8; ++r)
#pragma unroll
    for (int c = 0; c < NC; ++c) acc[r][c] = 0.f;

  const int lr = tid >> 3;        // 0..31
  const int lk = (tid & 7) << 2;  // 0,4,..,28

  for (int kk = 0; kk < 128; kk += BK) {
#pragma unroll
    for (int s = 0; s < 4; ++s) {
      int r = lr + s * 32;
      int grow = brow + r;
      float4 v = make_float4(0.f, 0.f, 0.f, 0.f);
      if (grow < n) v = *(const float4*)&A[(size_t)grow * 128 + kk + lk];
      *(float4*)&sA[r][lk] = v;
    }
#pragma unroll
    for (int s = 0; s < DO / 32; ++s) {
      int r = lr + s * 32;
      float4 v = *(const float4*)&Wt[(size_t)r * 128 + kk + lk];
      *(float4*)&sW[r][lk] = v;
    }
    __syncthreads();
#pragma unroll
    for (int k4 = 0; k4 < BK; k4 += 4) {
      float4 a4[8], w4[NC];
#pragma unroll
      for (int r = 0; r < 8; ++r) a4[r] = *(const float4*)&sA[trow + (r << 4)][k4];
#pragma unroll
      for (int c = 0; c < NC; ++c) w4[c] = *(const float4*)&sW[tcol + (c << 4)][k4];
#pragma unroll
      for (int r = 0; r < 8; ++r)
#pragma unroll
        for (int c = 0; c < NC; ++c) {
          acc[r][c] += a4[r].x * w4[c].x;
          acc[r][c] += a4[r].y * w4[c].y;
          acc[r][c] += a4[r].z * w4[c].z;
          acc[r][c] += a4[r].w * w4[c].w;
        }
    }
    __syncthreads();
  }

#pragma unroll
  for (int r = 0; r < 8; ++r) {
    int grow = brow + trow + (r << 4);
    if (grow < n) {
      float dv = dinv[grow];
#pragma unroll
      for (int c = 0; c < NC; ++c) G[(size_t)grow * DO + tcol + (c << 4)] = dv * acc[r][c];
    }
  }
}

// ---------------- aggregation: Y[v] = dinv[v]*(G[v] + sum_{u in N(v)} G[u]) + b ----------------
// one wave per node; D=128: float2/lane (512B coalesced row); D=64: float/lane.

template <int D, bool RELU>
__global__ __launch_bounds__(256) void aggregate(const float* __restrict__ G, const float* __restrict__ dinv,
                                                 const float* __restrict__ bias, const int* __restrict__ row_ptr,
                                                 const int* __restrict__ col, float* __restrict__ Y, int n) {
  int v = (int)((blockIdx.x * 256 + threadIdx.x) >> 6);
  int lane = threadIdx.x & 63;
  if (v >= n) return;
  int s = row_ptr[v], e = row_ptr[v + 1];
  if constexpr (D == 128) {
    const float2* G2 = (const float2*)G;
    float2 acc = G2[(size_t)v * 64 + lane];  // self-loop term
    for (int t = s; t < e; ++t) {
      int u = col[t];
      float2 gv = G2[(size_t)u * 64 + lane];
      acc.x += gv.x;
      acc.y += gv.y;
    }
    float dv = dinv[v];
    float2 bb = ((const float2*)bias)[lane];
    float ox = fmaf(dv, acc.x, bb.x);
    float oy = fmaf(dv, acc.y, bb.y);
    if (RELU) { ox = fmaxf(ox, 0.f); oy = fmaxf(oy, 0.f); }
    ((float2*)Y)[(size_t)v * 64 + lane] = make_float2(ox, oy);
  } else {
    float acc = G[(size_t)v * 64 + lane];
    for (int t = s; t < e; ++t) {
      int u = col[t];
      acc += G[(size_t)u * 64 + lane];
    }
    float dv = dinv[v];
    float o = fmaf(dv, acc, bias[lane]);
    if (RELU) o = fmaxf(o, 0.f);
    Y[(size_t)v * 64 + lane] = o;
  }
}

// ---------------- launch ----------------

extern "C" void kernel_launch(void* const* d_in, const int* in_sizes, int n_in,
                              void* d_out, int out_size, void* d_ws, size_t ws_size,
                              hipStream_t stream) {
  const float* x = (const float*)d_in[0];
  const void* ei = d_in[1];
  const int N = in_sizes[0] / 128;
  const int E = in_sizes[1] / 2;
  const float* W[5] = {(const float*)d_in[2], (const float*)d_in[4], (const float*)d_in[6],
                       (const float*)d_in[8], (const float*)d_in[10]};
  const float* B[5] = {(const float*)d_in[3], (const float*)d_in[5], (const float*)d_in[7],
                       (const float*)d_in[9], (const float*)d_in[11]};

  char* p = (char*)d_ws;
  float* g = (float*)p;            p += (size_t)N * 128 * sizeof(float);
  float* y = (float*)p;            p += (size_t)N * 128 * sizeof(float);
  float* dinv = (float*)p;         p += (size_t)N * sizeof(float);
  int* deg = (int*)p;              p += (size_t)N * sizeof(int);
  int* fill = (int*)p;             p += (size_t)N * sizeof(int);
  int* col = (int*)p;              p += (size_t)E * sizeof(int);
  int* row_ptr = (int*)p;          p += (size_t)(N + 1) * sizeof(int);
  int* flag = (int*)p;             p += 16;

  hipMemsetAsync(deg, 0, (size_t)N * sizeof(int), stream);
  hipMemsetAsync(fill, 0, (size_t)N * sizeof(int), stream);

  k_detect<<<1, 256, 0, stream>>>((const int*)ei, flag, E);
  k_hist<<<(E + 255) / 256, 256, 0, stream>>>(ei, flag, deg, E, N);
  k_dinv<<<(N + 255) / 256, 256, 0, stream>>>(deg, dinv, N);
  k_scan<<<1, 1024, 0, stream>>>(deg, row_ptr, N);
  k_fill<<<(E + 255) / 256, 256, 0, stream>>>(ei, flag, row_ptr, fill, col, E, N);

  const int gb = (N + 127) / 128;
  const int ab = (N * 64 + 255) / 256;

  // layer 0: x -> g -> y
  gemm_xwt<128><<<gb, 256, 0, stream>>>(x, W[0], dinv, g, N);
  aggregate<128, true><<<ab, 256, 0, stream>>>(g, dinv, B[0], row_ptr, col, y, N);
  // layers 1..3: y -> g -> y
  for (int l = 1; l <= 3; ++l) {
    gemm_xwt<128><<<gb, 256, 0, stream>>>(y, W[l], dinv, g, N);
    aggregate<128, true><<<ab, 256, 0, stream>>>(g, dinv, B[l], row_ptr, col, y, N);
  }
  // layer 4: y -> g(64) -> d_out
  gemm_xwt<64><<<gb, 256, 0, stream>>>(y, W[4], dinv, g, N);
  aggregate<64, false><<<ab, 256, 0, stream>>>(g, dinv, B[4], row_ptr, col, (float*)d_out, N);
}

// Round 2
// 696.949 us; speedup vs baseline: 1.1123x; 1.1123x over previous
//
#include <hip/hip_runtime.h>
#include <math.h>

// GCN: out = D^-1/2 (A+I) D^-1/2 (x W^T) + b per layer, ReLU between layers.
// CSR built once per call; per layer: fp32 tiled GEMM with dinv folded into
// epilogue, then wave-per-node gather-sum, epilogue y = dinv*sum + b (+ReLU).
// R1: replaced single-block scan (89us, 1 CU busy) with 3-phase multiblock scan.

// ---------------- graph build ----------------

// Detect whether edge_index is stored as int64 (hi words of nonneg values == 0)
__global__ __launch_bounds__(256) void k_detect(const int* __restrict__ ei, int* __restrict__ flag, int E) {
  __shared__ int nonzero;
  if (threadIdx.x == 0) nonzero = 0;
  __syncthreads();
  int idx = threadIdx.x;
  if (idx < E && idx < 256) {
    if (ei[2 * idx + 1] != 0) atomicOr(&nonzero, 1);
  }
  __syncthreads();
  if (threadIdx.x == 0) *flag = (nonzero == 0) ? 1 : 0;  // 1 => int64 layout
}

__device__ __forceinline__ int edge_at(const void* ei, int is64, long long idx) {
  if (is64) return (int)((const long long*)ei)[idx];
  return ((const int*)ei)[idx];
}

__global__ __launch_bounds__(256) void k_hist(const void* __restrict__ ei, const int* __restrict__ flag,
                                              int* __restrict__ deg, int E, int n) {
  int i = blockIdx.x * 256 + threadIdx.x;
  if (i >= E) return;
  int is64 = *flag;
  int v = edge_at(ei, is64, (long long)E + i);  // dst row
  if ((unsigned)v < (unsigned)n) atomicAdd(&deg[v], 1);
}

__global__ __launch_bounds__(256) void k_dinv(const int* __restrict__ deg, float* __restrict__ dinv, int n) {
  int i = blockIdx.x * 256 + threadIdx.x;
  if (i < n) dinv[i] = 1.0f / sqrtf((float)(deg[i] + 1));  // +1 self-loop; always > 0
}

// ---- 3-phase scan: deg[n] -> row_ptr[n+1] (exclusive; row_ptr[0]=0) ----
// Phase A: per-block (1024 elems) total. Phase B: exclusive scan of block
// totals (single small block; nb ~ 49 for N=50000). Phase C: per-block local
// scan + block offset.

__global__ __launch_bounds__(256) void k_scan_part(const int* __restrict__ deg, int* __restrict__ bsum, int n) {
  int base = blockIdx.x * 1024 + threadIdx.x * 4;
  int s = 0;
#pragma unroll
  for (int j = 0; j < 4; ++j) {
    int i = base + j;
    if (i < n) s += deg[i];
  }
  __shared__ int wtot[4];
  int lane = threadIdx.x & 63, w = threadIdx.x >> 6;
#pragma unroll
  for (int off = 32; off > 0; off >>= 1) s += __shfl_down(s, off, 64);
  if (lane == 0) wtot[w] = s;
  __syncthreads();
  if (threadIdx.x == 0) bsum[blockIdx.x] = wtot[0] + wtot[1] + wtot[2] + wtot[3];
}

__global__ __launch_bounds__(1024) void k_scan_sums(int* __restrict__ bsum, int nb) {
  // single block; Hillis-Steele over up to 1024 block sums -> exclusive
  __shared__ int buf[1024];
  int t = threadIdx.x;
  int v = (t < nb) ? bsum[t] : 0;
  buf[t] = v;
  __syncthreads();
  for (int off = 1; off < 1024; off <<= 1) {
    int u = (t >= off) ? buf[t - off] : 0;
    __syncthreads();
    buf[t] += u;
    __syncthreads();
  }
  if (t < nb) bsum[t] = buf[t] - v;  // exclusive
}

__global__ __launch_bounds__(256) void k_scan_final(const int* __restrict__ deg, const int* __restrict__ bsum,
                                                    int* __restrict__ row_ptr, int n) {
  int t = threadIdx.x;
  int base = blockIdx.x * 1024 + t * 4;
  int v[4];
  int s = 0;
#pragma unroll
  for (int j = 0; j < 4; ++j) {
    int i = base + j;
    v[j] = (i < n) ? deg[i] : 0;
    s += v[j];
  }
  int lane = t & 63, w = t >> 6;
  int incl = s;
#pragma unroll
  for (int off = 1; off < 64; off <<= 1) {
    int u = __shfl_up(incl, off, 64);
    if (lane >= off) incl += u;
  }
  __shared__ int wtot[4];
  if (lane == 63) wtot[w] = incl;
  __syncthreads();
  int woff = 0;
  for (int i = 0; i < w; ++i) woff += wtot[i];
  int run = bsum[blockIdx.x] + woff + incl - s;  // exclusive prefix for this thread
#pragma unroll
  for (int j = 0; j < 4; ++j) {
    run += v[j];
    int i = base + j;
    if (i < n) row_ptr[i + 1] = run;
  }
  if (blockIdx.x == 0 && t == 0) row_ptr[0] = 0;
}

__global__ __launch_bounds__(256) void k_fill(const void* __restrict__ ei, const int* __restrict__ flag,
                                              const int* __restrict__ row_ptr, int* __restrict__ fill,
                                              int* __restrict__ col, int E, int n) {
  int i = blockIdx.x * 256 + threadIdx.x;
  if (i >= E) return;
  int is64 = *flag;
  int s = edge_at(ei, is64, i);                  // src row
  int v = edge_at(ei, is64, (long long)E + i);   // dst row
  if ((unsigned)v < (unsigned)n && (unsigned)s < (unsigned)n) {
    int pos = atomicAdd(&fill[v], 1);
    col[row_ptr[v] + pos] = s;
  }
}

// ---------------- GEMM: G[n,DO] = dinv[:,None] * (A[n,128] @ W[DO,128]^T) ----------------

template <int DO>
__global__ __launch_bounds__(256) void gemm_xwt(const float* __restrict__ A, const float* __restrict__ Wt,
                                                const float* __restrict__ dinv, float* __restrict__ G, int n) {
  constexpr int BK = 32;
  constexpr int SS = BK + 4;   // 36 floats: keeps float4 alignment, spreads superbanks
  constexpr int NC = DO / 16;
  __shared__ float sA[128][SS];
  __shared__ float sW[DO][SS];
  const int tid = threadIdx.x;
  const int trow = tid >> 4;   // 0..15
  const int tcol = tid & 15;   // 0..15
  const int brow = blockIdx.x * 128;

  float acc[8][NC];
#pragma unroll
  for (int r = 0; r < 8; ++r)
#pragma unroll
    for (int c = 0; c < NC; ++c) acc[r][c] = 0.f;

  const int lr = tid >> 3;        // 0..31
  const int lk = (tid & 7) << 2;  // 0,4,..,28

  for (int kk = 0; kk < 128; kk += BK) {
#pragma unroll
    for (int s = 0; s < 4; ++s) {
      int r = lr + s * 32;
      int grow = brow + r;
      float4 v = make_float4(0.f, 0.f, 0.f, 0.f);
      if (grow < n) v = *(const float4*)&A[(size_t)grow * 128 + kk + lk];
      *(float4*)&sA[r][lk] = v;
    }
#pragma unroll
    for (int s = 0; s < DO / 32; ++s) {
      int r = lr + s * 32;
      float4 v = *(const float4*)&Wt[(size_t)r * 128 + kk + lk];
      *(float4*)&sW[r][lk] = v;
    }
    __syncthreads();
#pragma unroll
    for (int k4 = 0; k4 < BK; k4 += 4) {
      float4 a4[8], w4[NC];
#pragma unroll
      for (int r = 0; r < 8; ++r) a4[r] = *(const float4*)&sA[trow + (r << 4)][k4];
#pragma unroll
      for (int c = 0; c < NC; ++c) w4[c] = *(const float4*)&sW[tcol + (c << 4)][k4];
#pragma unroll
      for (int r = 0; r < 8; ++r)
#pragma unroll
        for (int c = 0; c < NC; ++c) {
          acc[r][c] += a4[r].x * w4[c].x;
          acc[r][c] += a4[r].y * w4[c].y;
          acc[r][c] += a4[r].z * w4[c].z;
          acc[r][c] += a4[r].w * w4[c].w;
        }
    }
    __syncthreads();
  }

#pragma unroll
  for (int r = 0; r < 8; ++r) {
    int grow = brow + trow + (r << 4);
    if (grow < n) {
      float dv = dinv[grow];
#pragma unroll
      for (int c = 0; c < NC; ++c) G[(size_t)grow * DO + tcol + (c << 4)] = dv * acc[r][c];
    }
  }
}

// ---------------- aggregation: Y[v] = dinv[v]*(G[v] + sum_{u in N(v)} G[u]) + b ----------------

template <int D, bool RELU>
__global__ __launch_bounds__(256) void aggregate(const float* __restrict__ G, const float* __restrict__ dinv,
                                                 const float* __restrict__ bias, const int* __restrict__ row_ptr,
                                                 const int* __restrict__ col, float* __restrict__ Y, int n) {
  int v = (int)((blockIdx.x * 256 + threadIdx.x) >> 6);
  int lane = threadIdx.x & 63;
  if (v >= n) return;
  int s = row_ptr[v], e = row_ptr[v + 1];
  if constexpr (D == 128) {
    const float2* G2 = (const float2*)G;
    float2 acc = G2[(size_t)v * 64 + lane];  // self-loop term
    for (int t = s; t < e; ++t) {
      int u = col[t];
      float2 gv = G2[(size_t)u * 64 + lane];
      acc.x += gv.x;
      acc.y += gv.y;
    }
    float dv = dinv[v];
    float2 bb = ((const float2*)bias)[lane];
    float ox = fmaf(dv, acc.x, bb.x);
    float oy = fmaf(dv, acc.y, bb.y);
    if (RELU) { ox = fmaxf(ox, 0.f); oy = fmaxf(oy, 0.f); }
    ((float2*)Y)[(size_t)v * 64 + lane] = make_float2(ox, oy);
  } else {
    float acc = G[(size_t)v * 64 + lane];
    for (int t = s; t < e; ++t) {
      int u = col[t];
      acc += G[(size_t)u * 64 + lane];
    }
    float dv = dinv[v];
    float o = fmaf(dv, acc, bias[lane]);
    if (RELU) o = fmaxf(o, 0.f);
    Y[(size_t)v * 64 + lane] = o;
  }
}

// ---------------- launch ----------------

extern "C" void kernel_launch(void* const* d_in, const int* in_sizes, int n_in,
                              void* d_out, int out_size, void* d_ws, size_t ws_size,
                              hipStream_t stream) {
  const float* x = (const float*)d_in[0];
  const void* ei = d_in[1];
  const int N = in_sizes[0] / 128;
  const int E = in_sizes[1] / 2;
  const float* W[5] = {(const float*)d_in[2], (const float*)d_in[4], (const float*)d_in[6],
                       (const float*)d_in[8], (const float*)d_in[10]};
  const float* B[5] = {(const float*)d_in[3], (const float*)d_in[5], (const float*)d_in[7],
                       (const float*)d_in[9], (const float*)d_in[11]};

  char* p = (char*)d_ws;
  float* g = (float*)p;            p += (size_t)N * 128 * sizeof(float);
  float* y = (float*)p;            p += (size_t)N * 128 * sizeof(float);
  float* dinv = (float*)p;         p += (size_t)N * sizeof(float);
  int* deg = (int*)p;              p += (size_t)N * sizeof(int);
  int* fill = (int*)p;             p += (size_t)N * sizeof(int);
  int* col = (int*)p;              p += (size_t)E * sizeof(int);
  int* row_ptr = (int*)p;          p += (size_t)(N + 1) * sizeof(int);
  int* bsum = (int*)p;             p += 4096 * sizeof(int);
  int* flag = (int*)p;             p += 16;

  hipMemsetAsync(deg, 0, (size_t)N * sizeof(int), stream);
  hipMemsetAsync(fill, 0, (size_t)N * sizeof(int), stream);

  const int nb = (N + 1023) / 1024;

  k_detect<<<1, 256, 0, stream>>>((const int*)ei, flag, E);
  k_hist<<<(E + 255) / 256, 256, 0, stream>>>(ei, flag, deg, E, N);
  k_dinv<<<(N + 255) / 256, 256, 0, stream>>>(deg, dinv, N);
  k_scan_part<<<nb, 256, 0, stream>>>(deg, bsum, N);
  k_scan_sums<<<1, 1024, 0, stream>>>(bsum, nb);
  k_scan_final<<<nb, 256, 0, stream>>>(deg, bsum, row_ptr, N);
  k_fill<<<(E + 255) / 256, 256, 0, stream>>>(ei, flag, row_ptr, fill, col, E, N);

  const int gb = (N + 127) / 128;
  const int ab = (N * 64 + 255) / 256;

  // layer 0: x -> g -> y
  gemm_xwt<128><<<gb, 256, 0, stream>>>(x, W[0], dinv, g, N);
  aggregate<128, true><<<ab, 256, 0, stream>>>(g, dinv, B[0], row_ptr, col, y, N);
  // layers 1..3: y -> g -> y
  for (int l = 1; l <= 3; ++l) {
    gemm_xwt<128><<<gb, 256, 0, stream>>>(y, W[l], dinv, g, N);
    aggregate<128, true><<<ab, 256, 0, stream>>>(g, dinv, B[l], row_ptr, col, y, N);
  }
  // layer 4: y -> g(64) -> d_out
  gemm_xwt<64><<<gb, 256, 0, stream>>>(y, W[4], dinv, g, N);
  aggregate<64, false><<<ab, 256, 0, stream>>>(g, dinv, B[4], row_ptr, col, (float*)d_out, N);
}

// Round 3
// 437.698 us; speedup vs baseline: 1.7711x; 1.5923x over previous
//
#include <hip/hip_runtime.h>
#include <hip/hip_fp16.h>
#include <math.h>

// GCN: out = D^-1/2 (A+I) D^-1/2 (x W^T) + b per layer, ReLU between layers.
// CSR built once per call; per layer: fp32 tiled GEMM (epilogue g = dinv.*h,
// stored FP16), then wave-per-node gather-sum with batched col loads + 4-deep
// ILP, epilogue y = dinv*sum + b (+ReLU) in fp32.
// R1: multiblock scan (k_scan 89us -> ~8us). R2: fp16 G + gather ILP.

// ---------------- graph build ----------------

__global__ __launch_bounds__(256) void k_detect(const int* __restrict__ ei, int* __restrict__ flag, int E) {
  __shared__ int nonzero;
  if (threadIdx.x == 0) nonzero = 0;
  __syncthreads();
  int idx = threadIdx.x;
  if (idx < E && idx < 256) {
    if (ei[2 * idx + 1] != 0) atomicOr(&nonzero, 1);
  }
  __syncthreads();
  if (threadIdx.x == 0) *flag = (nonzero == 0) ? 1 : 0;  // 1 => int64 layout
}

__device__ __forceinline__ int edge_at(const void* ei, int is64, long long idx) {
  if (is64) return (int)((const long long*)ei)[idx];
  return ((const int*)ei)[idx];
}

__global__ __launch_bounds__(256) void k_hist(const void* __restrict__ ei, const int* __restrict__ flag,
                                              int* __restrict__ deg, int E, int n) {
  int i = blockIdx.x * 256 + threadIdx.x;
  if (i >= E) return;
  int is64 = *flag;
  int v = edge_at(ei, is64, (long long)E + i);  // dst row
  if ((unsigned)v < (unsigned)n) atomicAdd(&deg[v], 1);
}

__global__ __launch_bounds__(256) void k_dinv(const int* __restrict__ deg, float* __restrict__ dinv, int n) {
  int i = blockIdx.x * 256 + threadIdx.x;
  if (i < n) dinv[i] = 1.0f / sqrtf((float)(deg[i] + 1));  // +1 self-loop; always > 0
}

// ---- 3-phase scan: deg[n] -> row_ptr[n+1] (exclusive; row_ptr[0]=0) ----

__global__ __launch_bounds__(256) void k_scan_part(const int* __restrict__ deg, int* __restrict__ bsum, int n) {
  int base = blockIdx.x * 1024 + threadIdx.x * 4;
  int s = 0;
#pragma unroll
  for (int j = 0; j < 4; ++j) {
    int i = base + j;
    if (i < n) s += deg[i];
  }
  __shared__ int wtot[4];
  int lane = threadIdx.x & 63, w = threadIdx.x >> 6;
#pragma unroll
  for (int off = 32; off > 0; off >>= 1) s += __shfl_down(s, off, 64);
  if (lane == 0) wtot[w] = s;
  __syncthreads();
  if (threadIdx.x == 0) bsum[blockIdx.x] = wtot[0] + wtot[1] + wtot[2] + wtot[3];
}

__global__ __launch_bounds__(1024) void k_scan_sums(int* __restrict__ bsum, int nb) {
  __shared__ int buf[1024];
  int t = threadIdx.x;
  int v = (t < nb) ? bsum[t] : 0;
  buf[t] = v;
  __syncthreads();
  for (int off = 1; off < 1024; off <<= 1) {
    int u = (t >= off) ? buf[t - off] : 0;
    __syncthreads();
    buf[t] += u;
    __syncthreads();
  }
  if (t < nb) bsum[t] = buf[t] - v;  // exclusive
}

__global__ __launch_bounds__(256) void k_scan_final(const int* __restrict__ deg, const int* __restrict__ bsum,
                                                    int* __restrict__ row_ptr, int n) {
  int t = threadIdx.x;
  int base = blockIdx.x * 1024 + t * 4;
  int v[4];
  int s = 0;
#pragma unroll
  for (int j = 0; j < 4; ++j) {
    int i = base + j;
    v[j] = (i < n) ? deg[i] : 0;
    s += v[j];
  }
  int lane = t & 63, w = t >> 6;
  int incl = s;
#pragma unroll
  for (int off = 1; off < 64; off <<= 1) {
    int u = __shfl_up(incl, off, 64);
    if (lane >= off) incl += u;
  }
  __shared__ int wtot[4];
  if (lane == 63) wtot[w] = incl;
  __syncthreads();
  int woff = 0;
  for (int i = 0; i < w; ++i) woff += wtot[i];
  int run = bsum[blockIdx.x] + woff + incl - s;  // exclusive prefix for this thread
#pragma unroll
  for (int j = 0; j < 4; ++j) {
    run += v[j];
    int i = base + j;
    if (i < n) row_ptr[i + 1] = run;
  }
  if (blockIdx.x == 0 && t == 0) row_ptr[0] = 0;
}

__global__ __launch_bounds__(256) void k_fill(const void* __restrict__ ei, const int* __restrict__ flag,
                                              const int* __restrict__ row_ptr, int* __restrict__ fill,
                                              int* __restrict__ col, int E, int n) {
  int i = blockIdx.x * 256 + threadIdx.x;
  if (i >= E) return;
  int is64 = *flag;
  int s = edge_at(ei, is64, i);                  // src row
  int v = edge_at(ei, is64, (long long)E + i);   // dst row
  if ((unsigned)v < (unsigned)n && (unsigned)s < (unsigned)n) {
    int pos = atomicAdd(&fill[v], 1);
    col[row_ptr[v] + pos] = s;
  }
}

// ---------------- GEMM: G[n,DO] = fp16( dinv[:,None] * (A[n,128] @ W[DO,128]^T) ) ----------------

template <int DO>
__global__ __launch_bounds__(256) void gemm_xwt(const float* __restrict__ A, const float* __restrict__ Wt,
                                                const float* __restrict__ dinv, __half* __restrict__ G, int n) {
  constexpr int BK = 32;
  constexpr int SS = BK + 4;
  constexpr int NC = DO / 16;
  __shared__ float sA[128][SS];
  __shared__ float sW[DO][SS];
  const int tid = threadIdx.x;
  const int trow = tid >> 4;
  const int tcol = tid & 15;
  const int brow = blockIdx.x * 128;

  float acc[8][NC];
#pragma unroll
  for (int r = 0; r < 8; ++r)
#pragma unroll
    for (int c = 0; c < NC; ++c) acc[r][c] = 0.f;

  const int lr = tid >> 3;
  const int lk = (tid & 7) << 2;

  for (int kk = 0; kk < 128; kk += BK) {
#pragma unroll
    for (int s = 0; s < 4; ++s) {
      int r = lr + s * 32;
      int grow = brow + r;
      float4 v = make_float4(0.f, 0.f, 0.f, 0.f);
      if (grow < n) v = *(const float4*)&A[(size_t)grow * 128 + kk + lk];
      *(float4*)&sA[r][lk] = v;
    }
#pragma unroll
    for (int s = 0; s < DO / 32; ++s) {
      int r = lr + s * 32;
      float4 v = *(const float4*)&Wt[(size_t)r * 128 + kk + lk];
      *(float4*)&sW[r][lk] = v;
    }
    __syncthreads();
#pragma unroll
    for (int k4 = 0; k4 < BK; k4 += 4) {
      float4 a4[8], w4[NC];
#pragma unroll
      for (int r = 0; r < 8; ++r) a4[r] = *(const float4*)&sA[trow + (r << 4)][k4];
#pragma unroll
      for (int c = 0; c < NC; ++c) w4[c] = *(const float4*)&sW[tcol + (c << 4)][k4];
#pragma unroll
      for (int r = 0; r < 8; ++r)
#pragma unroll
        for (int c = 0; c < NC; ++c) {
          acc[r][c] += a4[r].x * w4[c].x;
          acc[r][c] += a4[r].y * w4[c].y;
          acc[r][c] += a4[r].z * w4[c].z;
          acc[r][c] += a4[r].w * w4[c].w;
        }
    }
    __syncthreads();
  }

#pragma unroll
  for (int r = 0; r < 8; ++r) {
    int grow = brow + trow + (r << 4);
    if (grow < n) {
      float dv = dinv[grow];
#pragma unroll
      for (int c = 0; c < NC; ++c) G[(size_t)grow * DO + tcol + (c << 4)] = __float2half(dv * acc[r][c]);
    }
  }
}

// ---------------- aggregation: Y[v] = dinv[v]*(G[v] + sum_{u in N(v)} G[u]) + b ----------------
// wave per node; fp16 G rows (D=128: 256B, lane reads uint=half2; D=64: 128B,
// lane reads ushort). Batched coalesced col loads + shfl broadcast; 4 ILP chains.

__device__ __forceinline__ float2 h2f(unsigned int u) {
  __half2 h = *(__half2*)&u;
  return __half22float2(h);
}

template <bool RELU>
__global__ __launch_bounds__(256) void aggregate128(const unsigned int* __restrict__ G, const float* __restrict__ dinv,
                                                    const float* __restrict__ bias, const int* __restrict__ rp,
                                                    const int* __restrict__ col, float* __restrict__ Y, int n) {
  int v = (int)((blockIdx.x * 256 + threadIdx.x) >> 6);
  int lane = threadIdx.x & 63;
  if (v >= n) return;
  int s = rp[v], e = rp[v + 1];
  float2 a0 = h2f(G[(size_t)v * 64 + lane]);  // self-loop term
  float2 a1 = make_float2(0.f, 0.f), a2 = make_float2(0.f, 0.f), a3 = make_float2(0.f, 0.f);
  int t = s;
  while (t < e) {
    int batch = e - t;
    if (batch > 64) batch = 64;
    int ci = col[t + (lane < batch ? lane : batch - 1)];
    int j = 0;
    for (; j + 4 <= batch; j += 4) {
      int u0 = __shfl(ci, j, 64), u1 = __shfl(ci, j + 1, 64);
      int u2 = __shfl(ci, j + 2, 64), u3 = __shfl(ci, j + 3, 64);
      unsigned int g0 = G[(size_t)u0 * 64 + lane];
      unsigned int g1 = G[(size_t)u1 * 64 + lane];
      unsigned int g2 = G[(size_t)u2 * 64 + lane];
      unsigned int g3 = G[(size_t)u3 * 64 + lane];
      float2 f0 = h2f(g0), f1 = h2f(g1), f2 = h2f(g2), f3 = h2f(g3);
      a0.x += f0.x; a0.y += f0.y;
      a1.x += f1.x; a1.y += f1.y;
      a2.x += f2.x; a2.y += f2.y;
      a3.x += f3.x; a3.y += f3.y;
    }
    for (; j < batch; ++j) {
      int u = __shfl(ci, j, 64);
      float2 f = h2f(G[(size_t)u * 64 + lane]);
      a0.x += f.x; a0.y += f.y;
    }
    t += batch;
  }
  float sx = (a0.x + a1.x) + (a2.x + a3.x);
  float sy = (a0.y + a1.y) + (a2.y + a3.y);
  float dv = dinv[v];
  float2 bb = ((const float2*)bias)[lane];
  float ox = fmaf(dv, sx, bb.x);
  float oy = fmaf(dv, sy, bb.y);
  if (RELU) { ox = fmaxf(ox, 0.f); oy = fmaxf(oy, 0.f); }
  ((float2*)Y)[(size_t)v * 64 + lane] = make_float2(ox, oy);
}

__global__ __launch_bounds__(256) void aggregate64(const unsigned short* __restrict__ G, const float* __restrict__ dinv,
                                                   const float* __restrict__ bias, const int* __restrict__ rp,
                                                   const int* __restrict__ col, float* __restrict__ Y, int n) {
  int v = (int)((blockIdx.x * 256 + threadIdx.x) >> 6);
  int lane = threadIdx.x & 63;
  if (v >= n) return;
  int s = rp[v], e = rp[v + 1];
  float a0 = __half2float(*(const __half*)&G[(size_t)v * 64 + lane]);
  float a1 = 0.f, a2 = 0.f, a3 = 0.f;
  int t = s;
  while (t < e) {
    int batch = e - t;
    if (batch > 64) batch = 64;
    int ci = col[t + (lane < batch ? lane : batch - 1)];
    int j = 0;
    for (; j + 4 <= batch; j += 4) {
      int u0 = __shfl(ci, j, 64), u1 = __shfl(ci, j + 1, 64);
      int u2 = __shfl(ci, j + 2, 64), u3 = __shfl(ci, j + 3, 64);
      unsigned short g0 = G[(size_t)u0 * 64 + lane];
      unsigned short g1 = G[(size_t)u1 * 64 + lane];
      unsigned short g2 = G[(size_t)u2 * 64 + lane];
      unsigned short g3 = G[(size_t)u3 * 64 + lane];
      a0 += __half2float(*(const __half*)&g0);
      a1 += __half2float(*(const __half*)&g1);
      a2 += __half2float(*(const __half*)&g2);
      a3 += __half2float(*(const __half*)&g3);
    }
    for (; j < batch; ++j) {
      int u = __shfl(ci, j, 64);
      unsigned short g = G[(size_t)u * 64 + lane];
      a0 += __half2float(*(const __half*)&g);
    }
    t += batch;
  }
  float sum = (a0 + a1) + (a2 + a3);
  float dv = dinv[v];
  float o = fmaf(dv, sum, bias[lane]);
  Y[(size_t)v * 64 + lane] = o;
}

// ---------------- launch ----------------

extern "C" void kernel_launch(void* const* d_in, const int* in_sizes, int n_in,
                              void* d_out, int out_size, void* d_ws, size_t ws_size,
                              hipStream_t stream) {
  const float* x = (const float*)d_in[0];
  const void* ei = d_in[1];
  const int N = in_sizes[0] / 128;
  const int E = in_sizes[1] / 2;
  const float* W[5] = {(const float*)d_in[2], (const float*)d_in[4], (const float*)d_in[6],
                       (const float*)d_in[8], (const float*)d_in[10]};
  const float* B[5] = {(const float*)d_in[3], (const float*)d_in[5], (const float*)d_in[7],
                       (const float*)d_in[9], (const float*)d_in[11]};

  char* p = (char*)d_ws;
  __half* g = (__half*)p;          p += (size_t)N * 128 * sizeof(__half);
  float* y = (float*)p;            p += (size_t)N * 128 * sizeof(float);
  float* dinv = (float*)p;         p += (size_t)N * sizeof(float);
  int* deg = (int*)p;              p += (size_t)N * sizeof(int);
  int* fill = (int*)p;             p += (size_t)N * sizeof(int);
  int* col = (int*)p;              p += (size_t)E * sizeof(int);
  int* row_ptr = (int*)p;          p += (size_t)(N + 1) * sizeof(int);
  int* bsum = (int*)p;             p += 4096 * sizeof(int);
  int* flag = (int*)p;             p += 16;

  hipMemsetAsync(deg, 0, (size_t)N * sizeof(int), stream);
  hipMemsetAsync(fill, 0, (size_t)N * sizeof(int), stream);

  const int nb = (N + 1023) / 1024;

  k_detect<<<1, 256, 0, stream>>>((const int*)ei, flag, E);
  k_hist<<<(E + 255) / 256, 256, 0, stream>>>(ei, flag, deg, E, N);
  k_dinv<<<(N + 255) / 256, 256, 0, stream>>>(deg, dinv, N);
  k_scan_part<<<nb, 256, 0, stream>>>(deg, bsum, N);
  k_scan_sums<<<1, 1024, 0, stream>>>(bsum, nb);
  k_scan_final<<<nb, 256, 0, stream>>>(deg, bsum, row_ptr, N);
  k_fill<<<(E + 255) / 256, 256, 0, stream>>>(ei, flag, row_ptr, fill, col, E, N);

  const int gb = (N + 127) / 128;
  const int ab = (N * 64 + 255) / 256;

  gemm_xwt<128><<<gb, 256, 0, stream>>>(x, W[0], dinv, g, N);
  aggregate128<true><<<ab, 256, 0, stream>>>((const unsigned int*)g, dinv, B[0], row_ptr, col, y, N);
  for (int l = 1; l <= 3; ++l) {
    gemm_xwt<128><<<gb, 256, 0, stream>>>(y, W[l], dinv, g, N);
    aggregate128<true><<<ab, 256, 0, stream>>>((const unsigned int*)g, dinv, B[l], row_ptr, col, y, N);
  }
  gemm_xwt<64><<<gb, 256, 0, stream>>>(y, W[4], dinv, g, N);
  aggregate64<<<ab, 256, 0, stream>>>((const unsigned short*)g, dinv, B[4], row_ptr, col, (float*)d_out, N);
}

// Round 4
// 367.037 us; speedup vs baseline: 2.1120x; 1.1925x over previous
//
#include <hip/hip_runtime.h>
#include <hip/hip_fp16.h>
#include <math.h>

// GCN: out = D^-1/2 (A+I) D^-1/2 (x W^T) + b per layer, ReLU between layers.
// R1: multiblock scan. R2: fp16 G + gather ILP (aggregate at compulsory-fetch
// floor, ~2.4TB/s fabric). R3: GEMM -> MFMA split-fp16 (y stored as h+r fp16
// pair, exact to 2^-22; x@W^T = xh*Wh + xh*Wr + xr*Wh on matrix cores).

typedef _Float16 f16x8 __attribute__((ext_vector_type(8)));
typedef float f32x4 __attribute__((ext_vector_type(4)));

// ---------------- graph build ----------------

__global__ __launch_bounds__(256) void k_detect(const int* __restrict__ ei, int* __restrict__ flag, int E) {
  __shared__ int nonzero;
  if (threadIdx.x == 0) nonzero = 0;
  __syncthreads();
  int idx = threadIdx.x;
  if (idx < E && idx < 256) {
    if (ei[2 * idx + 1] != 0) atomicOr(&nonzero, 1);
  }
  __syncthreads();
  if (threadIdx.x == 0) *flag = (nonzero == 0) ? 1 : 0;  // 1 => int64 layout
}

__device__ __forceinline__ int edge_at(const void* ei, int is64, long long idx) {
  if (is64) return (int)((const long long*)ei)[idx];
  return ((const int*)ei)[idx];
}

__global__ __launch_bounds__(256) void k_hist(const void* __restrict__ ei, const int* __restrict__ flag,
                                              int* __restrict__ deg, int E, int n) {
  int i = blockIdx.x * 256 + threadIdx.x;
  if (i >= E) return;
  int is64 = *flag;
  int v = edge_at(ei, is64, (long long)E + i);  // dst row
  if ((unsigned)v < (unsigned)n) atomicAdd(&deg[v], 1);
}

__global__ __launch_bounds__(256) void k_dinv(const int* __restrict__ deg, float* __restrict__ dinv, int n) {
  int i = blockIdx.x * 256 + threadIdx.x;
  if (i < n) dinv[i] = 1.0f / sqrtf((float)(deg[i] + 1));
}

__global__ __launch_bounds__(256) void k_scan_part(const int* __restrict__ deg, int* __restrict__ bsum, int n) {
  int base = blockIdx.x * 1024 + threadIdx.x * 4;
  int s = 0;
#pragma unroll
  for (int j = 0; j < 4; ++j) {
    int i = base + j;
    if (i < n) s += deg[i];
  }
  __shared__ int wtot[4];
  int lane = threadIdx.x & 63, w = threadIdx.x >> 6;
#pragma unroll
  for (int off = 32; off > 0; off >>= 1) s += __shfl_down(s, off, 64);
  if (lane == 0) wtot[w] = s;
  __syncthreads();
  if (threadIdx.x == 0) bsum[blockIdx.x] = wtot[0] + wtot[1] + wtot[2] + wtot[3];
}

__global__ __launch_bounds__(1024) void k_scan_sums(int* __restrict__ bsum, int nb) {
  __shared__ int buf[1024];
  int t = threadIdx.x;
  int v = (t < nb) ? bsum[t] : 0;
  buf[t] = v;
  __syncthreads();
  for (int off = 1; off < 1024; off <<= 1) {
    int u = (t >= off) ? buf[t - off] : 0;
    __syncthreads();
    buf[t] += u;
    __syncthreads();
  }
  if (t < nb) bsum[t] = buf[t] - v;  // exclusive
}

__global__ __launch_bounds__(256) void k_scan_final(const int* __restrict__ deg, const int* __restrict__ bsum,
                                                    int* __restrict__ row_ptr, int n) {
  int t = threadIdx.x;
  int base = blockIdx.x * 1024 + t * 4;
  int v[4];
  int s = 0;
#pragma unroll
  for (int j = 0; j < 4; ++j) {
    int i = base + j;
    v[j] = (i < n) ? deg[i] : 0;
    s += v[j];
  }
  int lane = t & 63, w = t >> 6;
  int incl = s;
#pragma unroll
  for (int off = 1; off < 64; off <<= 1) {
    int u = __shfl_up(incl, off, 64);
    if (lane >= off) incl += u;
  }
  __shared__ int wtot[4];
  if (lane == 63) wtot[w] = incl;
  __syncthreads();
  int woff = 0;
  for (int i = 0; i < w; ++i) woff += wtot[i];
  int run = bsum[blockIdx.x] + woff + incl - s;
#pragma unroll
  for (int j = 0; j < 4; ++j) {
    run += v[j];
    int i = base + j;
    if (i < n) row_ptr[i + 1] = run;
  }
  if (blockIdx.x == 0 && t == 0) row_ptr[0] = 0;
}

__global__ __launch_bounds__(256) void k_fill(const void* __restrict__ ei, const int* __restrict__ flag,
                                              const int* __restrict__ row_ptr, int* __restrict__ fill,
                                              int* __restrict__ col, int E, int n) {
  int i = blockIdx.x * 256 + threadIdx.x;
  if (i >= E) return;
  int is64 = *flag;
  int s = edge_at(ei, is64, i);
  int v = edge_at(ei, is64, (long long)E + i);
  if ((unsigned)v < (unsigned)n && (unsigned)s < (unsigned)n) {
    int pos = atomicAdd(&fill[v], 1);
    col[row_ptr[v] + pos] = s;
  }
}

// ---------------- fp32 -> (h, r) fp16 splits ----------------

__global__ __launch_bounds__(256) void k_split_x(const float* __restrict__ X, unsigned int* __restrict__ Xh,
                                                 unsigned int* __restrict__ Xr, int n2) {
  int i = blockIdx.x * 256 + threadIdx.x;  // pair index
  if (i >= n2) return;
  float2 v = ((const float2*)X)[i];
  __half hx = __float2half(v.x), hy = __float2half(v.y);
  float rx = v.x - __half2float(hx), ry = v.y - __half2float(hy);
  __half rxh = __float2half(rx), ryh = __float2half(ry);
  unsigned int ph = ((unsigned int)*(unsigned short*)&hy << 16) | *(unsigned short*)&hx;
  unsigned int pr = ((unsigned int)*(unsigned short*)&ryh << 16) | *(unsigned short*)&rxh;
  Xh[i] = ph;
  Xr[i] = pr;
}

__global__ __launch_bounds__(256) void k_split_w(const float* __restrict__ W, unsigned short* __restrict__ Wh,
                                                 unsigned short* __restrict__ Wr, int cnt) {
  int i = blockIdx.x * 256 + threadIdx.x;
  if (i >= cnt) return;
  float v = W[i];
  __half h = __float2half(v);
  float r = v - __half2float(h);
  __half rh = __float2half(r);
  Wh[i] = *(unsigned short*)&h;
  Wr[i] = *(unsigned short*)&rh;
}

// ---------------- MFMA GEMM: G[n,DO] = fp16( dinv * ((Xh+Xr) @ (Wh+Wr)^T) ) ----------------
// 256 thr = 4 waves; wave owns 16 rows; W (h+r) staged in LDS with XOR chunk
// swizzle (chunk' = chunk ^ (row&7)) so B-frag ds_read_b128 is ~2-way (free).
// A-frags read from global (16 rows stay L1-resident across kb).

template <int DO>
__global__ __launch_bounds__(256) void gemm_mfma(const unsigned short* __restrict__ Xh,
                                                 const unsigned short* __restrict__ Xr,
                                                 const unsigned short* __restrict__ Wh,
                                                 const unsigned short* __restrict__ Wr,
                                                 const float* __restrict__ dinv, __half* __restrict__ G, int n) {
  constexpr int NCG = DO / 16;
  __shared__ unsigned short sWh[DO * 128];
  __shared__ unsigned short sWr[DO * 128];
  const int tid = threadIdx.x;

  // stage W with swizzle: elem block t covers row=t>>4, chunk=t&15 (8 halves)
#pragma unroll
  for (int it = 0; it < DO / 16; ++it) {
    int t = it * 256 + tid;
    int row = t >> 4, ch = t & 15;
    int sch = ch ^ (row & 7);
    const uint4* gh = (const uint4*)&Wh[(size_t)t * 8];
    const uint4* gr = (const uint4*)&Wr[(size_t)t * 8];
    *(uint4*)&sWh[row * 128 + sch * 8] = *gh;
    *(uint4*)&sWr[row * 128 + sch * 8] = *gr;
  }

  const int wv = tid >> 6;
  const int l = tid & 63;
  const int m = l & 15;       // row within wave tile / col of C
  const int ks = l >> 4;      // k-split 0..3
  const int gr0 = blockIdx.x * 64 + wv * 16;
  const int arow = gr0 + m;

  // preload all A-frags (global), overlapped with W staging
  f16x8 ah[4], ar[4];
  const f16x8 z8 = {0, 0, 0, 0, 0, 0, 0, 0};
#pragma unroll
  for (int kb = 0; kb < 4; ++kb) {
    int koff = kb * 32 + ks * 8;
    if (arow < n) {
      ah[kb] = *(const f16x8*)&Xh[(size_t)arow * 128 + koff];
      ar[kb] = *(const f16x8*)&Xr[(size_t)arow * 128 + koff];
    } else {
      ah[kb] = z8;
      ar[kb] = z8;
    }
  }

  f32x4 acc[NCG];
#pragma unroll
  for (int c = 0; c < NCG; ++c) acc[c] = {0.f, 0.f, 0.f, 0.f};

  __syncthreads();

#pragma unroll
  for (int kb = 0; kb < 4; ++kb) {
    int ch = (kb * 4 + ks) ^ (m & 7);  // swizzled chunk for B row (cg*16+m): row&7 == m&7
#pragma unroll
    for (int c = 0; c < NCG; ++c) {
      int brow = c * 16 + m;
      f16x8 bh = *(const f16x8*)&sWh[brow * 128 + ch * 8];
      f16x8 br = *(const f16x8*)&sWr[brow * 128 + ch * 8];
      acc[c] = __builtin_amdgcn_mfma_f32_16x16x32_f16(ah[kb], bh, acc[c], 0, 0, 0);
      acc[c] = __builtin_amdgcn_mfma_f32_16x16x32_f16(ah[kb], br, acc[c], 0, 0, 0);
      acc[c] = __builtin_amdgcn_mfma_f32_16x16x32_f16(ar[kb], bh, acc[c], 0, 0, 0);
    }
  }

  // epilogue: C/D layout col = l&15, row = (l>>4)*4 + reg
  int r0 = gr0 + ks * 4;
  float dv[4];
#pragma unroll
  for (int i = 0; i < 4; ++i) dv[i] = (r0 + i < n) ? dinv[r0 + i] : 0.f;
#pragma unroll
  for (int c = 0; c < NCG; ++c) {
#pragma unroll
    for (int i = 0; i < 4; ++i) {
      int row = r0 + i;
      if (row < n) G[(size_t)row * DO + c * 16 + m] = __float2half(dv[i] * acc[c][i]);
    }
  }
}

// ---------------- aggregation ----------------

__device__ __forceinline__ float2 h2f(unsigned int u) {
  __half2 h = *(__half2*)&u;
  return __half22float2(h);
}

// D=128 layers: writes split (h,r) fp16 pair for next layer's MFMA GEMM.
__global__ __launch_bounds__(256) void aggregate128(const unsigned int* __restrict__ G, const float* __restrict__ dinv,
                                                    const float* __restrict__ bias, const int* __restrict__ rp,
                                                    const int* __restrict__ col, unsigned int* __restrict__ Yh,
                                                    unsigned int* __restrict__ Yr, int n) {
  int v = (int)((blockIdx.x * 256 + threadIdx.x) >> 6);
  int lane = threadIdx.x & 63;
  if (v >= n) return;
  int s = rp[v], e = rp[v + 1];
  float2 a0 = h2f(G[(size_t)v * 64 + lane]);  // self-loop
  float2 a1 = make_float2(0.f, 0.f), a2 = make_float2(0.f, 0.f), a3 = make_float2(0.f, 0.f);
  int t = s;
  while (t < e) {
    int batch = e - t;
    if (batch > 64) batch = 64;
    int ci = col[t + (lane < batch ? lane : batch - 1)];
    int j = 0;
    for (; j + 4 <= batch; j += 4) {
      int u0 = __shfl(ci, j, 64), u1 = __shfl(ci, j + 1, 64);
      int u2 = __shfl(ci, j + 2, 64), u3 = __shfl(ci, j + 3, 64);
      float2 f0 = h2f(G[(size_t)u0 * 64 + lane]);
      float2 f1 = h2f(G[(size_t)u1 * 64 + lane]);
      float2 f2 = h2f(G[(size_t)u2 * 64 + lane]);
      float2 f3 = h2f(G[(size_t)u3 * 64 + lane]);
      a0.x += f0.x; a0.y += f0.y;
      a1.x += f1.x; a1.y += f1.y;
      a2.x += f2.x; a2.y += f2.y;
      a3.x += f3.x; a3.y += f3.y;
    }
    for (; j < batch; ++j) {
      int u = __shfl(ci, j, 64);
      float2 f = h2f(G[(size_t)u * 64 + lane]);
      a0.x += f.x; a0.y += f.y;
    }
    t += batch;
  }
  float sx = (a0.x + a1.x) + (a2.x + a3.x);
  float sy = (a0.y + a1.y) + (a2.y + a3.y);
  float dv = dinv[v];
  float2 bb = ((const float2*)bias)[lane];
  float ox = fmaxf(fmaf(dv, sx, bb.x), 0.f);  // ReLU (all 128-wide layers have it)
  float oy = fmaxf(fmaf(dv, sy, bb.y), 0.f);
  __half hx = __float2half(ox), hy = __float2half(oy);
  float rx = ox - __half2float(hx), ry = oy - __half2float(hy);
  __half rxh = __float2half(rx), ryh = __float2half(ry);
  size_t o = (size_t)v * 64 + lane;
  Yh[o] = ((unsigned int)*(unsigned short*)&hy << 16) | *(unsigned short*)&hx;
  Yr[o] = ((unsigned int)*(unsigned short*)&ryh << 16) | *(unsigned short*)&rxh;
}

__global__ __launch_bounds__(256) void aggregate64(const unsigned short* __restrict__ G, const float* __restrict__ dinv,
                                                   const float* __restrict__ bias, const int* __restrict__ rp,
                                                   const int* __restrict__ col, float* __restrict__ Y, int n) {
  int v = (int)((blockIdx.x * 256 + threadIdx.x) >> 6);
  int lane = threadIdx.x & 63;
  if (v >= n) return;
  int s = rp[v], e = rp[v + 1];
  float a0 = __half2float(*(const __half*)&G[(size_t)v * 64 + lane]);
  float a1 = 0.f, a2 = 0.f, a3 = 0.f;
  int t = s;
  while (t < e) {
    int batch = e - t;
    if (batch > 64) batch = 64;
    int ci = col[t + (lane < batch ? lane : batch - 1)];
    int j = 0;
    for (; j + 4 <= batch; j += 4) {
      int u0 = __shfl(ci, j, 64), u1 = __shfl(ci, j + 1, 64);
      int u2 = __shfl(ci, j + 2, 64), u3 = __shfl(ci, j + 3, 64);
      unsigned short g0 = G[(size_t)u0 * 64 + lane];
      unsigned short g1 = G[(size_t)u1 * 64 + lane];
      unsigned short g2 = G[(size_t)u2 * 64 + lane];
      unsigned short g3 = G[(size_t)u3 * 64 + lane];
      a0 += __half2float(*(const __half*)&g0);
      a1 += __half2float(*(const __half*)&g1);
      a2 += __half2float(*(const __half*)&g2);
      a3 += __half2float(*(const __half*)&g3);
    }
    for (; j < batch; ++j) {
      int u = __shfl(ci, j, 64);
      unsigned short g = G[(size_t)u * 64 + lane];
      a0 += __half2float(*(const __half*)&g);
    }
    t += batch;
  }
  float sum = (a0 + a1) + (a2 + a3);
  Y[(size_t)v * 64 + lane] = fmaf(dinv[v], sum, bias[lane]);
}

// ---------------- launch ----------------

extern "C" void kernel_launch(void* const* d_in, const int* in_sizes, int n_in,
                              void* d_out, int out_size, void* d_ws, size_t ws_size,
                              hipStream_t stream) {
  const float* x = (const float*)d_in[0];
  const void* ei = d_in[1];
  const int N = in_sizes[0] / 128;
  const int E = in_sizes[1] / 2;
  const float* W[5] = {(const float*)d_in[2], (const float*)d_in[4], (const float*)d_in[6],
                       (const float*)d_in[8], (const float*)d_in[10]};
  const float* B[5] = {(const float*)d_in[3], (const float*)d_in[5], (const float*)d_in[7],
                       (const float*)d_in[9], (const float*)d_in[11]};
  const int wcnt[5] = {128 * 128, 128 * 128, 128 * 128, 128 * 128, 64 * 128};

  char* p = (char*)d_ws;
  unsigned short* xyh = (unsigned short*)p;  p += (size_t)N * 128 * 2;   // activations h (fp16)
  unsigned short* xyr = (unsigned short*)p;  p += (size_t)N * 128 * 2;   // activations r (fp16)
  __half* g = (__half*)p;                    p += (size_t)N * 128 * 2;   // post-GEMM dinv.*h
  unsigned short* wh = (unsigned short*)p;   p += (size_t)5 * 16384 * 2;
  unsigned short* wr = (unsigned short*)p;   p += (size_t)5 * 16384 * 2;
  float* dinv = (float*)p;                   p += (size_t)N * 4;
  int* deg = (int*)p;                        p += (size_t)N * 4;
  int* fill = (int*)p;                       p += (size_t)N * 4;
  int* col = (int*)p;                        p += (size_t)E * 4;
  int* row_ptr = (int*)p;                    p += (size_t)(N + 1) * 4;
  int* bsum = (int*)p;                       p += 4096 * 4;
  int* flag = (int*)p;                       p += 16;

  hipMemsetAsync(deg, 0, (size_t)N * sizeof(int), stream);
  hipMemsetAsync(fill, 0, (size_t)N * sizeof(int), stream);

  const int nb = (N + 1023) / 1024;

  k_detect<<<1, 256, 0, stream>>>((const int*)ei, flag, E);
  k_hist<<<(E + 255) / 256, 256, 0, stream>>>(ei, flag, deg, E, N);
  k_dinv<<<(N + 255) / 256, 256, 0, stream>>>(deg, dinv, N);
  k_scan_part<<<nb, 256, 0, stream>>>(deg, bsum, N);
  k_scan_sums<<<1, 1024, 0, stream>>>(bsum, nb);
  k_scan_final<<<nb, 256, 0, stream>>>(deg, bsum, row_ptr, N);
  k_fill<<<(E + 255) / 256, 256, 0, stream>>>(ei, flag, row_ptr, fill, col, E, N);

  k_split_x<<<(N * 64 + 255) / 256, 256, 0, stream>>>(x, (unsigned int*)xyh, (unsigned int*)xyr, N * 64);
  for (int l = 0; l < 5; ++l)
    k_split_w<<<(wcnt[l] + 255) / 256, 256, 0, stream>>>(W[l], wh + l * 16384, wr + l * 16384, wcnt[l]);

  const int gb = (N + 63) / 64;
  const int ab = (N * 64 + 255) / 256;

  for (int l = 0; l < 4; ++l) {
    gemm_mfma<128><<<gb, 256, 0, stream>>>(xyh, xyr, wh + l * 16384, wr + l * 16384, dinv, g, N);
    aggregate128<<<ab, 256, 0, stream>>>((const unsigned int*)g, dinv, B[l], row_ptr, col,
                                         (unsigned int*)xyh, (unsigned int*)xyr, N);
  }
  gemm_mfma<64><<<gb, 256, 0, stream>>>(xyh, xyr, wh + 4 * 16384, wr + 4 * 16384, dinv, g, N);
  aggregate64<<<ab, 256, 0, stream>>>((const unsigned short*)g, dinv, B[4], row_ptr, col, (float*)d_out, N);
}